// Round 13
// baseline (353.909 us; speedup 1.0000x reference)
//
#include <hip/hip_runtime.h>

#define N_SRC   100000
#define N_TGT   50000
#define N_EDGES 1000000
#define NEG     0.2
#define NXCD    8
#define TPART   (N_TGT / NXCD)   // 6250
#define SPART   (N_SRC / NXCD)   // 12500

#define GBLK_S  1563             // ceil(N_SRC/64)
#define GBLK_T  782              // ceil(N_TGT/64)
#define GBLK    (GBLK_S + GBLK_T)          // 2345
#define HBLK    ((N_EDGES + 255) / 256)    // 3907
#define NGROUP  782              // 8-block groups: 3 gemm + 5 hist

// ===========================================================================
// CSR/CSC build + gather. Edge-score math in f64 (ill-conditioned row sums);
// msg matrices f32 (bf16 fatal, R6). R8: XCD-partitioned scatter. R11:
// readfirstlane GEMM + ILP gather. R12: atomic-free rank scatter. R13: GEMM
// and hist_rank fused into one fat kernel (disjoint inputs & bottleneck
// resources -> overlap).
// ===========================================================================

// ---------------------------------------------------------------------------
// Fused: per 8-block group, slots 0-2 are GEMM blocks (64 rows x 4 col-waves,
// LDS-staged x, s_load w — R11-proven body), slots 3-7 are hist blocks
// (256 edges each: rank_r/c[i] = atomicAdd on node counters).
// ---------------------------------------------------------------------------
#define XS 129
__global__ __launch_bounds__(256) void fused_gemm_hist(
    const float* __restrict__ x_source, const float* __restrict__ x_target,
    const float* __restrict__ w_s, const float* __restrict__ w_t,
    const float* __restrict__ att,
    float* __restrict__ s_msg, float* __restrict__ t_msg,
    double* __restrict__ es_d, double* __restrict__ et_d,
    const int* __restrict__ rows, const int* __restrict__ cols,
    int* __restrict__ cnt_r, int* __restrict__ cnt_c,
    int* __restrict__ rank_r, int* __restrict__ rank_c)
{
    __shared__ float xs[64 * XS];          // 33 KB
    __shared__ double eds[4][64];          //  2 KB
    const int grp  = blockIdx.x >> 3;
    const int slot = blockIdx.x & 7;
    const int tid  = threadIdx.x;

    if (slot >= 3) {
        // ---------------- hist branch ----------------
        const int hi = grp * 5 + (slot - 3);
        if (hi >= HBLK) return;
        const int i = hi * 256 + tid;
        if (i >= N_EDGES) return;
        rank_r[i] = atomicAdd(&cnt_r[rows[i]], 1);
        rank_c[i] = atomicAdd(&cnt_c[cols[i]], 1);
        return;
    }

    // ---------------- gemm branch ----------------
    const int gi = grp * 3 + slot;
    if (gi >= GBLK) return;

    const float* x; const float* w; int att_off, nrows, bblk;
    float* msg; double* evec;
    if (gi < GBLK_S) { x = x_source; w = w_s; att_off = 0;  nrows = N_SRC;
                       msg = s_msg;  evec = es_d; bblk = gi; }
    else             { x = x_target; w = w_t; att_off = 64; nrows = N_TGT;
                       msg = t_msg;  evec = et_d; bblk = gi - GBLK_S; }

    const int lane = tid & 63;
    const int part = tid >> 6;
    const int c0   = __builtin_amdgcn_readfirstlane(part << 4);
    const int row0 = bblk * 64;
    const int row  = row0 + lane;
    const bool act = row < nrows;

    #pragma unroll
    for (int it = 0; it < 8; ++it) {
        const int fid = tid + it * 256;
        const int r = fid >> 5, q = fid & 31;
        if (row0 + r < nrows) {
            const float4 v = *(const float4*)(x + (size_t)(row0 + r) * 128 + 4 * q);
            float* d = &xs[r * XS + 4 * q];
            d[0] = v.x; d[1] = v.y; d[2] = v.z; d[3] = v.w;
        }
    }
    __syncthreads();

    float acc[16];
    #pragma unroll
    for (int c = 0; c < 16; ++c) acc[c] = 0.f;

    const int xbase = lane * XS;
    for (int kc = 0; kc < 128; kc += 16) {
        #pragma unroll
        for (int kk = 0; kk < 16; ++kk) {
            const float xk = xs[xbase + kc + kk];
            const float* wr = w + (size_t)(kc + kk) * 64 + c0;  // scalar addr
            #pragma unroll
            for (int c = 0; c < 16; ++c)
                acc[c] = fmaf(xk, wr[c], acc[c]);
        }
    }

    double e = 0.0;
    #pragma unroll
    for (int c = 0; c < 16; ++c)
        e += (double)acc[c] * (double)att[att_off + c0 + c];
    eds[part][lane] = e;
    __syncthreads();
    if (part == 0 && act)
        evec[row] = eds[0][lane] + eds[1][lane] + eds[2][lane] + eds[3][lane];

    if (act) {
        float* mo = msg + (size_t)row * 64 + c0;
        #pragma unroll
        for (int q = 0; q < 4; ++q)
            *(float4*)(mo + 4 * q) = *(float4*)(acc + 4 * q);
    }
}

// ---------------------------------------------------------------------------
// Exclusive scan, tiled + coalesced. block 0 -> rows (N_TGT), 1 -> cols (N_SRC).
// ---------------------------------------------------------------------------
__global__ __launch_bounds__(1024) void scan_two(
    const int* __restrict__ cnt_r, const int* __restrict__ cnt_c,
    int* __restrict__ ptr_r, int* __restrict__ ptr_c)
{
    const int n    = blockIdx.x ? N_SRC : N_TGT;
    const int* cnt = blockIdx.x ? cnt_c : cnt_r;
    int* ptr       = blockIdx.x ? ptr_c : ptr_r;
    const int tid  = threadIdx.x;
    const int lane = tid & 63, wid = tid >> 6;

    __shared__ int wsum[16];
    __shared__ int s_carry;
    if (tid == 0) s_carry = 0;
    __syncthreads();

    for (int base = 0; base < n; base += 4096) {
        const int idx = base + tid * 4;
        int4 v = make_int4(0, 0, 0, 0);
        if (idx + 3 < n) {
            v = *(const int4*)(cnt + idx);
        } else if (idx < n) {
            v.x = cnt[idx];
            if (idx + 1 < n) v.y = cnt[idx + 1];
            if (idx + 2 < n) v.z = cnt[idx + 2];
        }
        const int s = v.x + v.y + v.z + v.w;

        int p = s;
        #pragma unroll
        for (int d = 1; d < 64; d <<= 1) {
            int t = __shfl_up(p, d);
            if (lane >= d) p += t;
        }
        if (lane == 63) wsum[wid] = p;
        __syncthreads();
        if (tid == 0) {
            int a = 0;
            #pragma unroll
            for (int i = 0; i < 16; ++i) { int t = wsum[i]; wsum[i] = a; a += t; }
        }
        __syncthreads();

        int run = s_carry + wsum[wid] + (p - s);
        if (idx     < n) ptr[idx]     = run; run += v.x;
        if (idx + 1 < n) ptr[idx + 1] = run; run += v.y;
        if (idx + 2 < n) ptr[idx + 2] = run; run += v.z;
        if (idx + 3 < n) ptr[idx + 3] = run; run += v.w;

        __syncthreads();
        if (tid == 1023) s_carry = run;
        __syncthreads();
    }
    if (tid == 0) ptr[n] = s_carry;
}

// ---------------------------------------------------------------------------
// Scatter, XCD-partitioned (R8) + atomic-free (R12): slot = ptr[node]+rank[i].
// ---------------------------------------------------------------------------
__global__ __launch_bounds__(256) void scatter_part(
    const int* __restrict__ rows, const int* __restrict__ cols,
    const float* __restrict__ nbhd,
    const int* __restrict__ ptr_r, const int* __restrict__ ptr_c,
    const int* __restrict__ rank_r, const int* __restrict__ rank_c,
    unsigned long long* __restrict__ srtT, unsigned long long* __restrict__ srtS)
{
    const int xcd  = blockIdx.x & (NXCD - 1);
    const int ibx  = blockIdx.x >> 3;
    const int step = (gridDim.x >> 3) * blockDim.x;
    const int lo_r = xcd * TPART, lo_c = xcd * SPART;

    for (int i = ibx * blockDim.x + threadIdx.x; i < N_EDGES; i += step) {
        const int r = rows[i], c = cols[i];
        const bool mr = (unsigned)(r - lo_r) < TPART;
        const bool mc = (unsigned)(c - lo_c) < SPART;
        if (!(mr | mc)) continue;
        const unsigned long long nb =
            (unsigned long long)(unsigned)__float_as_int(nbhd[i]) << 32;
        if (mr) srtT[ptr_r[r] + rank_r[i]] = nb | (unsigned)c;
        if (mc) srtS[ptr_c[c] + rank_c[i]] = nb | (unsigned)r;
    }
}

// ---------------------------------------------------------------------------
// Gather: one wave per output row, lane = feature. Scores in f64; 4-way acc
// ILP (R11); payload double-buffer prefetch (R13).
// ---------------------------------------------------------------------------
__global__ __launch_bounds__(256) void gather_both(
    const int2* __restrict__ srtT, const int* __restrict__ ptr_r,
    const float* __restrict__ s_msg, float* __restrict__ msg_tgt,
    const int2* __restrict__ srtS, const int* __restrict__ ptr_c,
    const float* __restrict__ t_msg, float* __restrict__ msg_src,
    const double* __restrict__ es_d, const double* __restrict__ et_d)
{
    const int gw   = (blockIdx.x * blockDim.x + threadIdx.x) >> 6;
    const int lane = threadIdx.x & 63;

    const int2* srt; const int* ptr; const float* min_; float* out;
    const double* other_d; double base; int row;
    if (gw < N_TGT) {
        srt = srtT; ptr = ptr_r; min_ = s_msg; out = msg_tgt;
        other_d = es_d; row = gw; base = et_d[row];
    } else {
        row = gw - N_TGT;
        if (row >= N_SRC) return;
        srt = srtS; ptr = ptr_c; min_ = t_msg; out = msg_src;
        other_d = et_d; base = es_d[row];
    }

    const int b = ptr[row], e = ptr[row + 1];
    double den = 0.0;
    double a0 = 0.0, a1 = 0.0, a2 = 0.0, a3 = 0.0;

    int2 pay = make_int2(0, 0);
    if (lane < e - b) pay = srt[b + lane];

    for (int j0 = b; j0 < e; j0 += 64) {
        const int m = e - j0;
        // prefetch next payload block before the FMA chain
        int2 nxt = make_int2(0, 0);
        if (j0 + 64 < e && lane < m - 64) nxt = srt[j0 + 64 + lane];

        int oidx = 0; double v = 0.0; float wf = 0.f;
        if (lane < m) {
            oidx = pay.x;
            const float nb = __int_as_float(pay.y);
            const double sv = base + other_d[oidx];
            v = (sv >= 0.0) ? sv : NEG * sv;
            wf = (float)(v * (double)nb);
        }
        den += v;

        const int cnt = m < 64 ? m : 64;
        int j = 0;
        for (; j + 3 < cnt; j += 4) {
            const int   c0_ = __shfl(oidx, j);     const float w0 = __shfl(wf, j);
            const int   c1_ = __shfl(oidx, j + 1); const float w1 = __shfl(wf, j + 1);
            const int   c2_ = __shfl(oidx, j + 2); const float w2 = __shfl(wf, j + 2);
            const int   c3_ = __shfl(oidx, j + 3); const float w3 = __shfl(wf, j + 3);
            a0 += (double)w0 * (double)min_[(size_t)c0_ * 64 + lane];
            a1 += (double)w1 * (double)min_[(size_t)c1_ * 64 + lane];
            a2 += (double)w2 * (double)min_[(size_t)c2_ * 64 + lane];
            a3 += (double)w3 * (double)min_[(size_t)c3_ * 64 + lane];
        }
        for (; j < cnt; ++j) {
            const int   c = __shfl(oidx, j);
            const float w = __shfl(wf, j);
            a0 += (double)w * (double)min_[(size_t)c * 64 + lane];
        }
        pay = nxt;
    }
    #pragma unroll
    for (int s = 32; s; s >>= 1) den += __shfl_xor(den, s);
    const double inv = (den != 0.0) ? 1.0 / den : 0.0;
    const double acc = (a0 + a1) + (a2 + a3);
    out[(size_t)row * 64 + lane] = (float)(acc * inv);
}

// ===========================================================================
extern "C" void kernel_launch(void* const* d_in, const int* in_sizes, int n_in,
                              void* d_out, int out_size, void* d_ws, size_t ws_size,
                              hipStream_t stream)
{
    const float* x_source = (const float*)d_in[0];
    const float* x_target = (const float*)d_in[1];
    const float* w_s      = (const float*)d_in[2];
    const float* w_t      = (const float*)d_in[3];
    const float* att      = (const float*)d_in[4];
    const float* nbhd     = (const float*)d_in[5];
    const int*   rows     = (const int*)d_in[6];
    const int*   cols     = (const int*)d_in[7];

    float* out     = (float*)d_out;
    float* msg_src = out;                       // (N_SRC, 64)
    float* msg_tgt = out + (size_t)N_SRC * 64;  // (N_TGT, 64)

    char* ws = (char*)d_ws;
    // byte layout: total 65,400,016 B
    float*  s_msg  = (float*) (ws + 0);           // 25,600,000
    float*  t_msg  = (float*) (ws + 25600000);    // 12,800,000
    double* es_d   = (double*)(ws + 38400000);    //    800,000
    double* et_d   = (double*)(ws + 39200000);    //    400,000
    int*    cnt_r  = (int*)   (ws + 39600000);    //    200,000
    int*    cnt_c  = (int*)   (ws + 39800000);    //    400,000
    int*    ptr_r  = (int*)   (ws + 40200000);    //    200,004
    int*    ptr_c  = (int*)   (ws + 40400004);    //    400,004 (+8 pad)
    int*    rank_r = (int*)   (ws + 40800016);    //  4,000,000
    int*    rank_c = (int*)   (ws + 44800016);    //  4,000,000
    unsigned long long* srtT = (unsigned long long*)(ws + 48800016); // 8,000,000
    unsigned long long* srtS = (unsigned long long*)(ws + 56800016); // 8,000,000

    hipMemsetAsync(ws + 39600000, 0, 600000, stream);  // cnt_r + cnt_c

    fused_gemm_hist<<<NGROUP * 8, 256, 0, stream>>>(
        x_source, x_target, w_s, w_t, att,
        s_msg, t_msg, es_d, et_d,
        rows, cols, cnt_r, cnt_c, rank_r, rank_c);

    scan_two<<<2, 1024, 0, stream>>>(cnt_r, cnt_c, ptr_r, ptr_c);
    scatter_part<<<2048, 256, 0, stream>>>(
        rows, cols, nbhd, ptr_r, ptr_c, rank_r, rank_c, srtT, srtS);

    gather_both<<<(N_TGT + N_SRC + 3) / 4, 256, 0, stream>>>(
        (const int2*)srtT, ptr_r, s_msg, msg_tgt,
        (const int2*)srtS, ptr_c, t_msg, msg_src, es_d, et_d);
}

// Round 14
// 314.672 us; speedup vs baseline: 1.1247x; 1.1247x over previous
//
#include <hip/hip_runtime.h>

#define N_SRC   100000
#define N_TGT   50000
#define N_EDGES 1000000
#define NEG     0.2
#define NXCD    8
#define TPART   (N_TGT / NXCD)   // 6250
#define SPART   (N_SRC / NXCD)   // 12500

#define GBLK_S  1563             // ceil(N_SRC/64)
#define GBLK_T  782              // ceil(N_TGT/64)
#define GBLK    (GBLK_S + GBLK_T)          // 2345
#define HBLK    ((N_EDGES + 255) / 256)    // 3907
#define NGROUP  782              // 8-block groups: 3 gemm + 5 hist

// ===========================================================================
// R14: R13's gemm+hist fusion with the occupancy fix — x staged in TWO
// 64-col half-tiles so LDS drops 35 KB -> 18.7 KB (4 -> 8 blocks/CU).
// R13 failure mechanism was occupancy collapse (26%), not the overlap idea.
// Everything else identical to R12 (333 us best).
// ===========================================================================

// ---------------------------------------------------------------------------
#define XS2 65
__global__ __launch_bounds__(256) void fused_gemm_hist(
    const float* __restrict__ x_source, const float* __restrict__ x_target,
    const float* __restrict__ w_s, const float* __restrict__ w_t,
    const float* __restrict__ att,
    float* __restrict__ s_msg, float* __restrict__ t_msg,
    double* __restrict__ es_d, double* __restrict__ et_d,
    const int* __restrict__ rows, const int* __restrict__ cols,
    int* __restrict__ cnt_r, int* __restrict__ cnt_c,
    int* __restrict__ rank_r, int* __restrict__ rank_c)
{
    __shared__ float xs[64 * XS2];         // 16.6 KB
    __shared__ double eds[4][64];          //  2.0 KB
    const int grp  = blockIdx.x >> 3;
    const int slot = blockIdx.x & 7;
    const int tid  = threadIdx.x;

    if (slot >= 3) {
        // ---------------- hist branch (no LDS use) ----------------
        const int hi = grp * 5 + (slot - 3);
        if (hi >= HBLK) return;
        const int i = hi * 256 + tid;
        if (i >= N_EDGES) return;
        rank_r[i] = atomicAdd(&cnt_r[rows[i]], 1);
        rank_c[i] = atomicAdd(&cnt_c[cols[i]], 1);
        return;
    }

    // ---------------- gemm branch ----------------
    const int gi = grp * 3 + slot;
    if (gi >= GBLK) return;

    const float* x; const float* w; int att_off, nrows, bblk;
    float* msg; double* evec;
    if (gi < GBLK_S) { x = x_source; w = w_s; att_off = 0;  nrows = N_SRC;
                       msg = s_msg;  evec = es_d; bblk = gi; }
    else             { x = x_target; w = w_t; att_off = 64; nrows = N_TGT;
                       msg = t_msg;  evec = et_d; bblk = gi - GBLK_S; }

    const int lane = tid & 63;
    const int part = tid >> 6;
    const int c0   = __builtin_amdgcn_readfirstlane(part << 4);
    const int row0 = bblk * 64;
    const int row  = row0 + lane;
    const bool act = row < nrows;

    float acc[16];
    #pragma unroll
    for (int c = 0; c < 16; ++c) acc[c] = 0.f;

    const int xbase = lane * XS2;

    #pragma unroll
    for (int h = 0; h < 2; ++h) {          // two 64-col half-tiles of x
        __syncthreads();                   // prior half fully consumed
        #pragma unroll
        for (int it = 0; it < 4; ++it) {   // stage 64 rows x 64 floats
            const int fid = tid + it * 256;        // 0..1023
            const int r = fid >> 4, q = fid & 15;  // 16 float4 per row
            if (row0 + r < nrows) {
                const float4 v =
                    *(const float4*)(x + (size_t)(row0 + r) * 128 + h * 64 + 4 * q);
                float* d = &xs[r * XS2 + 4 * q];
                d[0] = v.x; d[1] = v.y; d[2] = v.z; d[3] = v.w;
            }
        }
        __syncthreads();

        for (int kc = 0; kc < 64; kc += 16) {
            #pragma unroll
            for (int kk = 0; kk < 16; ++kk) {
                const float xk = xs[xbase + kc + kk];
                const float* wr = w + (size_t)(h * 64 + kc + kk) * 64 + c0; // scalar
                #pragma unroll
                for (int c = 0; c < 16; ++c)
                    acc[c] = fmaf(xk, wr[c], acc[c]);
            }
        }
    }

    double e = 0.0;
    #pragma unroll
    for (int c = 0; c < 16; ++c)
        e += (double)acc[c] * (double)att[att_off + c0 + c];
    eds[part][lane] = e;
    __syncthreads();
    if (part == 0 && act)
        evec[row] = eds[0][lane] + eds[1][lane] + eds[2][lane] + eds[3][lane];

    if (act) {
        float* mo = msg + (size_t)row * 64 + c0;
        #pragma unroll
        for (int q = 0; q < 4; ++q)
            *(float4*)(mo + 4 * q) = *(float4*)(acc + 4 * q);
    }
}

// ---------------------------------------------------------------------------
// Exclusive scan, tiled + coalesced. block 0 -> rows (N_TGT), 1 -> cols (N_SRC).
// ---------------------------------------------------------------------------
__global__ __launch_bounds__(1024) void scan_two(
    const int* __restrict__ cnt_r, const int* __restrict__ cnt_c,
    int* __restrict__ ptr_r, int* __restrict__ ptr_c)
{
    const int n    = blockIdx.x ? N_SRC : N_TGT;
    const int* cnt = blockIdx.x ? cnt_c : cnt_r;
    int* ptr       = blockIdx.x ? ptr_c : ptr_r;
    const int tid  = threadIdx.x;
    const int lane = tid & 63, wid = tid >> 6;

    __shared__ int wsum[16];
    __shared__ int s_carry;
    if (tid == 0) s_carry = 0;
    __syncthreads();

    for (int base = 0; base < n; base += 4096) {
        const int idx = base + tid * 4;
        int4 v = make_int4(0, 0, 0, 0);
        if (idx + 3 < n) {
            v = *(const int4*)(cnt + idx);
        } else if (idx < n) {
            v.x = cnt[idx];
            if (idx + 1 < n) v.y = cnt[idx + 1];
            if (idx + 2 < n) v.z = cnt[idx + 2];
        }
        const int s = v.x + v.y + v.z + v.w;

        int p = s;
        #pragma unroll
        for (int d = 1; d < 64; d <<= 1) {
            int t = __shfl_up(p, d);
            if (lane >= d) p += t;
        }
        if (lane == 63) wsum[wid] = p;
        __syncthreads();
        if (tid == 0) {
            int a = 0;
            #pragma unroll
            for (int i = 0; i < 16; ++i) { int t = wsum[i]; wsum[i] = a; a += t; }
        }
        __syncthreads();

        int run = s_carry + wsum[wid] + (p - s);
        if (idx     < n) ptr[idx]     = run; run += v.x;
        if (idx + 1 < n) ptr[idx + 1] = run; run += v.y;
        if (idx + 2 < n) ptr[idx + 2] = run; run += v.z;
        if (idx + 3 < n) ptr[idx + 3] = run; run += v.w;

        __syncthreads();
        if (tid == 1023) s_carry = run;
        __syncthreads();
    }
    if (tid == 0) ptr[n] = s_carry;
}

// ---------------------------------------------------------------------------
// Scatter, XCD-partitioned (R8) + atomic-free (R12): slot = ptr[node]+rank[i].
// ---------------------------------------------------------------------------
__global__ __launch_bounds__(256) void scatter_part(
    const int* __restrict__ rows, const int* __restrict__ cols,
    const float* __restrict__ nbhd,
    const int* __restrict__ ptr_r, const int* __restrict__ ptr_c,
    const int* __restrict__ rank_r, const int* __restrict__ rank_c,
    unsigned long long* __restrict__ srtT, unsigned long long* __restrict__ srtS)
{
    const int xcd  = blockIdx.x & (NXCD - 1);
    const int ibx  = blockIdx.x >> 3;
    const int step = (gridDim.x >> 3) * blockDim.x;
    const int lo_r = xcd * TPART, lo_c = xcd * SPART;

    for (int i = ibx * blockDim.x + threadIdx.x; i < N_EDGES; i += step) {
        const int r = rows[i], c = cols[i];
        const bool mr = (unsigned)(r - lo_r) < TPART;
        const bool mc = (unsigned)(c - lo_c) < SPART;
        if (!(mr | mc)) continue;
        const unsigned long long nb =
            (unsigned long long)(unsigned)__float_as_int(nbhd[i]) << 32;
        if (mr) srtT[ptr_r[r] + rank_r[i]] = nb | (unsigned)c;
        if (mc) srtS[ptr_c[c] + rank_c[i]] = nb | (unsigned)r;
    }
}

// ---------------------------------------------------------------------------
// Gather (exact R12 version): one wave per output row, lane = feature.
// Scores in f64; 4-way acc ILP.
// ---------------------------------------------------------------------------
__global__ __launch_bounds__(256) void gather_both(
    const int2* __restrict__ srtT, const int* __restrict__ ptr_r,
    const float* __restrict__ s_msg, float* __restrict__ msg_tgt,
    const int2* __restrict__ srtS, const int* __restrict__ ptr_c,
    const float* __restrict__ t_msg, float* __restrict__ msg_src,
    const double* __restrict__ es_d, const double* __restrict__ et_d)
{
    const int gw   = (blockIdx.x * blockDim.x + threadIdx.x) >> 6;
    const int lane = threadIdx.x & 63;

    const int2* srt; const int* ptr; const float* min_; float* out;
    const double* other_d; double base; int row;
    if (gw < N_TGT) {
        srt = srtT; ptr = ptr_r; min_ = s_msg; out = msg_tgt;
        other_d = es_d; row = gw; base = et_d[row];
    } else {
        row = gw - N_TGT;
        if (row >= N_SRC) return;
        srt = srtS; ptr = ptr_c; min_ = t_msg; out = msg_src;
        other_d = et_d; base = es_d[row];
    }

    const int b = ptr[row], e = ptr[row + 1];
    double den = 0.0;
    double a0 = 0.0, a1 = 0.0, a2 = 0.0, a3 = 0.0;

    for (int j0 = b; j0 < e; j0 += 64) {
        const int m = e - j0;
        int oidx = 0; double v = 0.0; float wf = 0.f;
        if (lane < m) {
            const int2 pay = srt[j0 + lane];
            oidx = pay.x;
            const float nb = __int_as_float(pay.y);
            const double sv = base + other_d[oidx];
            v = (sv >= 0.0) ? sv : NEG * sv;
            wf = (float)(v * (double)nb);
        }
        den += v;

        const int cnt = m < 64 ? m : 64;
        int j = 0;
        for (; j + 3 < cnt; j += 4) {
            const int   c0_ = __shfl(oidx, j);     const float w0 = __shfl(wf, j);
            const int   c1_ = __shfl(oidx, j + 1); const float w1 = __shfl(wf, j + 1);
            const int   c2_ = __shfl(oidx, j + 2); const float w2 = __shfl(wf, j + 2);
            const int   c3_ = __shfl(oidx, j + 3); const float w3 = __shfl(wf, j + 3);
            a0 += (double)w0 * (double)min_[(size_t)c0_ * 64 + lane];
            a1 += (double)w1 * (double)min_[(size_t)c1_ * 64 + lane];
            a2 += (double)w2 * (double)min_[(size_t)c2_ * 64 + lane];
            a3 += (double)w3 * (double)min_[(size_t)c3_ * 64 + lane];
        }
        for (; j < cnt; ++j) {
            const int   c = __shfl(oidx, j);
            const float w = __shfl(wf, j);
            a0 += (double)w * (double)min_[(size_t)c * 64 + lane];
        }
    }
    #pragma unroll
    for (int s = 32; s; s >>= 1) den += __shfl_xor(den, s);
    const double inv = (den != 0.0) ? 1.0 / den : 0.0;
    const double acc = (a0 + a1) + (a2 + a3);
    out[(size_t)row * 64 + lane] = (float)(acc * inv);
}

// ===========================================================================
extern "C" void kernel_launch(void* const* d_in, const int* in_sizes, int n_in,
                              void* d_out, int out_size, void* d_ws, size_t ws_size,
                              hipStream_t stream)
{
    const float* x_source = (const float*)d_in[0];
    const float* x_target = (const float*)d_in[1];
    const float* w_s      = (const float*)d_in[2];
    const float* w_t      = (const float*)d_in[3];
    const float* att      = (const float*)d_in[4];
    const float* nbhd     = (const float*)d_in[5];
    const int*   rows     = (const int*)d_in[6];
    const int*   cols     = (const int*)d_in[7];

    float* out     = (float*)d_out;
    float* msg_src = out;                       // (N_SRC, 64)
    float* msg_tgt = out + (size_t)N_SRC * 64;  // (N_TGT, 64)

    char* ws = (char*)d_ws;
    // byte layout: total 65,400,016 B
    float*  s_msg  = (float*) (ws + 0);           // 25,600,000
    float*  t_msg  = (float*) (ws + 25600000);    // 12,800,000
    double* es_d   = (double*)(ws + 38400000);    //    800,000
    double* et_d   = (double*)(ws + 39200000);    //    400,000
    int*    cnt_r  = (int*)   (ws + 39600000);    //    200,000
    int*    cnt_c  = (int*)   (ws + 39800000);    //    400,000
    int*    ptr_r  = (int*)   (ws + 40200000);    //    200,004
    int*    ptr_c  = (int*)   (ws + 40400004);    //    400,004 (+8 pad)
    int*    rank_r = (int*)   (ws + 40800016);    //  4,000,000
    int*    rank_c = (int*)   (ws + 44800016);    //  4,000,000
    unsigned long long* srtT = (unsigned long long*)(ws + 48800016); // 8,000,000
    unsigned long long* srtS = (unsigned long long*)(ws + 56800016); // 8,000,000

    hipMemsetAsync(ws + 39600000, 0, 600000, stream);  // cnt_r + cnt_c

    fused_gemm_hist<<<NGROUP * 8, 256, 0, stream>>>(
        x_source, x_target, w_s, w_t, att,
        s_msg, t_msg, es_d, et_d,
        rows, cols, cnt_r, cnt_c, rank_r, rank_c);

    scan_two<<<2, 1024, 0, stream>>>(cnt_r, cnt_c, ptr_r, ptr_c);
    scatter_part<<<2048, 256, 0, stream>>>(
        rows, cols, nbhd, ptr_r, ptr_c, rank_r, rank_c, srtT, srtS);

    gather_both<<<(N_TGT + N_SRC + 3) / 4, 256, 0, stream>>>(
        (const int2*)srtT, ptr_r, s_msg, msg_tgt,
        (const int2*)srtS, ptr_c, t_msg, msg_src, es_d, et_d);
}

// Round 15
// 297.487 us; speedup vs baseline: 1.1897x; 1.0578x over previous
//
#include <hip/hip_runtime.h>

#define N_SRC   100000
#define N_TGT   50000
#define N_EDGES 1000000
#define NEG     0.2
#define NXCD    8
#define TPART   (N_TGT / NXCD)   // 6250
#define SPART   (N_SRC / NXCD)   // 12500

#define GBLK_S  1563             // ceil(N_SRC/64)
#define GBLK_T  782              // ceil(N_TGT/64)
#define GBLK    (GBLK_S + GBLK_T)          // 2345 gemm blocks
#define NHIST   1280             // hist blocks, grid-stride, dispatched FIRST

// ===========================================================================
// R15: fused gemm+hist with hist blocks FRONT-LOADED (R14's residual cost was
// in-order dispatch dilution of the latency-bound hist atomics). Gather
// numerator switched to f32 (cancellation lives only in den, kept f64).
// ===========================================================================

// ---------------------------------------------------------------------------
#define XS2 65
__global__ __launch_bounds__(256) void fused_gemm_hist(
    const float* __restrict__ x_source, const float* __restrict__ x_target,
    const float* __restrict__ w_s, const float* __restrict__ w_t,
    const float* __restrict__ att,
    float* __restrict__ s_msg, float* __restrict__ t_msg,
    double* __restrict__ es_d, double* __restrict__ et_d,
    const int* __restrict__ rows, const int* __restrict__ cols,
    int* __restrict__ cnt_r, int* __restrict__ cnt_c,
    int* __restrict__ rank_r, int* __restrict__ rank_c)
{
    __shared__ float xs[64 * XS2];         // 16.6 KB
    __shared__ double eds[4][64];          //  2.0 KB
    const int tid = threadIdx.x;

    if (blockIdx.x < NHIST) {
        // ---------------- hist branch: dispatched first, grid-stride ----------
        for (int i = blockIdx.x * 256 + tid; i < N_EDGES; i += NHIST * 256) {
            rank_r[i] = atomicAdd(&cnt_r[rows[i]], 1);
            rank_c[i] = atomicAdd(&cnt_c[cols[i]], 1);
        }
        return;
    }

    // ---------------- gemm branch ----------------
    const int gi = blockIdx.x - NHIST;

    const float* x; const float* w; int att_off, nrows, bblk;
    float* msg; double* evec;
    if (gi < GBLK_S) { x = x_source; w = w_s; att_off = 0;  nrows = N_SRC;
                       msg = s_msg;  evec = es_d; bblk = gi; }
    else             { x = x_target; w = w_t; att_off = 64; nrows = N_TGT;
                       msg = t_msg;  evec = et_d; bblk = gi - GBLK_S; }

    const int lane = tid & 63;
    const int part = tid >> 6;
    const int c0   = __builtin_amdgcn_readfirstlane(part << 4);
    const int row0 = bblk * 64;
    const int row  = row0 + lane;
    const bool act = row < nrows;

    float acc[16];
    #pragma unroll
    for (int c = 0; c < 16; ++c) acc[c] = 0.f;

    const int xbase = lane * XS2;

    #pragma unroll
    for (int h = 0; h < 2; ++h) {          // two 64-col half-tiles of x
        __syncthreads();                   // prior half fully consumed
        #pragma unroll
        for (int it = 0; it < 4; ++it) {   // stage 64 rows x 64 floats
            const int fid = tid + it * 256;        // 0..1023
            const int r = fid >> 4, q = fid & 15;  // 16 float4 per row
            if (row0 + r < nrows) {
                const float4 v =
                    *(const float4*)(x + (size_t)(row0 + r) * 128 + h * 64 + 4 * q);
                float* d = &xs[r * XS2 + 4 * q];
                d[0] = v.x; d[1] = v.y; d[2] = v.z; d[3] = v.w;
            }
        }
        __syncthreads();

        for (int kc = 0; kc < 64; kc += 16) {
            #pragma unroll
            for (int kk = 0; kk < 16; ++kk) {
                const float xk = xs[xbase + kc + kk];
                const float* wr = w + (size_t)(h * 64 + kc + kk) * 64 + c0; // scalar
                #pragma unroll
                for (int c = 0; c < 16; ++c)
                    acc[c] = fmaf(xk, wr[c], acc[c]);
            }
        }
    }

    double e = 0.0;
    #pragma unroll
    for (int c = 0; c < 16; ++c)
        e += (double)acc[c] * (double)att[att_off + c0 + c];
    eds[part][lane] = e;
    __syncthreads();
    if (part == 0 && act)
        evec[row] = eds[0][lane] + eds[1][lane] + eds[2][lane] + eds[3][lane];

    if (act) {
        float* mo = msg + (size_t)row * 64 + c0;
        #pragma unroll
        for (int q = 0; q < 4; ++q)
            *(float4*)(mo + 4 * q) = *(float4*)(acc + 4 * q);
    }
}

// ---------------------------------------------------------------------------
// Exclusive scan, tiled + coalesced. block 0 -> rows (N_TGT), 1 -> cols (N_SRC).
// ---------------------------------------------------------------------------
__global__ __launch_bounds__(1024) void scan_two(
    const int* __restrict__ cnt_r, const int* __restrict__ cnt_c,
    int* __restrict__ ptr_r, int* __restrict__ ptr_c)
{
    const int n    = blockIdx.x ? N_SRC : N_TGT;
    const int* cnt = blockIdx.x ? cnt_c : cnt_r;
    int* ptr       = blockIdx.x ? ptr_c : ptr_r;
    const int tid  = threadIdx.x;
    const int lane = tid & 63, wid = tid >> 6;

    __shared__ int wsum[16];
    __shared__ int s_carry;
    if (tid == 0) s_carry = 0;
    __syncthreads();

    for (int base = 0; base < n; base += 4096) {
        const int idx = base + tid * 4;
        int4 v = make_int4(0, 0, 0, 0);
        if (idx + 3 < n) {
            v = *(const int4*)(cnt + idx);
        } else if (idx < n) {
            v.x = cnt[idx];
            if (idx + 1 < n) v.y = cnt[idx + 1];
            if (idx + 2 < n) v.z = cnt[idx + 2];
        }
        const int s = v.x + v.y + v.z + v.w;

        int p = s;
        #pragma unroll
        for (int d = 1; d < 64; d <<= 1) {
            int t = __shfl_up(p, d);
            if (lane >= d) p += t;
        }
        if (lane == 63) wsum[wid] = p;
        __syncthreads();
        if (tid == 0) {
            int a = 0;
            #pragma unroll
            for (int i = 0; i < 16; ++i) { int t = wsum[i]; wsum[i] = a; a += t; }
        }
        __syncthreads();

        int run = s_carry + wsum[wid] + (p - s);
        if (idx     < n) ptr[idx]     = run; run += v.x;
        if (idx + 1 < n) ptr[idx + 1] = run; run += v.y;
        if (idx + 2 < n) ptr[idx + 2] = run; run += v.z;
        if (idx + 3 < n) ptr[idx + 3] = run; run += v.w;

        __syncthreads();
        if (tid == 1023) s_carry = run;
        __syncthreads();
    }
    if (tid == 0) ptr[n] = s_carry;
}

// ---------------------------------------------------------------------------
// Scatter, XCD-partitioned (R8) + atomic-free (R12): slot = ptr[node]+rank[i].
// ---------------------------------------------------------------------------
__global__ __launch_bounds__(256) void scatter_part(
    const int* __restrict__ rows, const int* __restrict__ cols,
    const float* __restrict__ nbhd,
    const int* __restrict__ ptr_r, const int* __restrict__ ptr_c,
    const int* __restrict__ rank_r, const int* __restrict__ rank_c,
    unsigned long long* __restrict__ srtT, unsigned long long* __restrict__ srtS)
{
    const int xcd  = blockIdx.x & (NXCD - 1);
    const int ibx  = blockIdx.x >> 3;
    const int step = (gridDim.x >> 3) * blockDim.x;
    const int lo_r = xcd * TPART, lo_c = xcd * SPART;

    for (int i = ibx * blockDim.x + threadIdx.x; i < N_EDGES; i += step) {
        const int r = rows[i], c = cols[i];
        const bool mr = (unsigned)(r - lo_r) < TPART;
        const bool mc = (unsigned)(c - lo_c) < SPART;
        if (!(mr | mc)) continue;
        const unsigned long long nb =
            (unsigned long long)(unsigned)__float_as_int(nbhd[i]) << 32;
        if (mr) srtT[ptr_r[r] + rank_r[i]] = nb | (unsigned)c;
        if (mc) srtS[ptr_c[c] + rank_c[i]] = nb | (unsigned)r;
    }
}

// ---------------------------------------------------------------------------
// Gather: one wave per output row, lane = feature. den in f64 (the ONLY
// cancelling sum); per-edge weight computed via f64 then cast; numerator
// accumulated in f32 x4 (no cancellation -> err ~ eps*|out|, negligible).
// ---------------------------------------------------------------------------
__global__ __launch_bounds__(256) void gather_both(
    const int2* __restrict__ srtT, const int* __restrict__ ptr_r,
    const float* __restrict__ s_msg, float* __restrict__ msg_tgt,
    const int2* __restrict__ srtS, const int* __restrict__ ptr_c,
    const float* __restrict__ t_msg, float* __restrict__ msg_src,
    const double* __restrict__ es_d, const double* __restrict__ et_d)
{
    const int gw   = (blockIdx.x * blockDim.x + threadIdx.x) >> 6;
    const int lane = threadIdx.x & 63;

    const int2* srt; const int* ptr; const float* min_; float* out;
    const double* other_d; double base; int row;
    if (gw < N_TGT) {
        srt = srtT; ptr = ptr_r; min_ = s_msg; out = msg_tgt;
        other_d = es_d; row = gw; base = et_d[row];
    } else {
        row = gw - N_TGT;
        if (row >= N_SRC) return;
        srt = srtS; ptr = ptr_c; min_ = t_msg; out = msg_src;
        other_d = et_d; base = es_d[row];
    }

    const int b = ptr[row], e = ptr[row + 1];
    double den = 0.0;
    float a0 = 0.f, a1 = 0.f, a2 = 0.f, a3 = 0.f;

    for (int j0 = b; j0 < e; j0 += 64) {
        const int m = e - j0;
        int oidx = 0; double v = 0.0; float wf = 0.f;
        if (lane < m) {
            const int2 pay = srt[j0 + lane];
            oidx = pay.x;
            const float nb = __int_as_float(pay.y);
            const double sv = base + other_d[oidx];
            v = (sv >= 0.0) ? sv : NEG * sv;
            wf = (float)(v * (double)nb);
        }
        den += v;

        const int cnt = m < 64 ? m : 64;
        int j = 0;
        for (; j + 3 < cnt; j += 4) {
            const int   c0_ = __shfl(oidx, j);     const float w0 = __shfl(wf, j);
            const int   c1_ = __shfl(oidx, j + 1); const float w1 = __shfl(wf, j + 1);
            const int   c2_ = __shfl(oidx, j + 2); const float w2 = __shfl(wf, j + 2);
            const int   c3_ = __shfl(oidx, j + 3); const float w3 = __shfl(wf, j + 3);
            a0 = fmaf(w0, min_[(size_t)c0_ * 64 + lane], a0);
            a1 = fmaf(w1, min_[(size_t)c1_ * 64 + lane], a1);
            a2 = fmaf(w2, min_[(size_t)c2_ * 64 + lane], a2);
            a3 = fmaf(w3, min_[(size_t)c3_ * 64 + lane], a3);
        }
        for (; j < cnt; ++j) {
            const int   c = __shfl(oidx, j);
            const float w = __shfl(wf, j);
            a0 = fmaf(w, min_[(size_t)c * 64 + lane], a0);
        }
    }
    #pragma unroll
    for (int s = 32; s; s >>= 1) den += __shfl_xor(den, s);
    const double inv = (den != 0.0) ? 1.0 / den : 0.0;
    const double acc = (double)((a0 + a1) + (a2 + a3));
    out[(size_t)row * 64 + lane] = (float)(acc * inv);
}

// ===========================================================================
extern "C" void kernel_launch(void* const* d_in, const int* in_sizes, int n_in,
                              void* d_out, int out_size, void* d_ws, size_t ws_size,
                              hipStream_t stream)
{
    const float* x_source = (const float*)d_in[0];
    const float* x_target = (const float*)d_in[1];
    const float* w_s      = (const float*)d_in[2];
    const float* w_t      = (const float*)d_in[3];
    const float* att      = (const float*)d_in[4];
    const float* nbhd     = (const float*)d_in[5];
    const int*   rows     = (const int*)d_in[6];
    const int*   cols     = (const int*)d_in[7];

    float* out     = (float*)d_out;
    float* msg_src = out;                       // (N_SRC, 64)
    float* msg_tgt = out + (size_t)N_SRC * 64;  // (N_TGT, 64)

    char* ws = (char*)d_ws;
    // byte layout: total 65,400,016 B
    float*  s_msg  = (float*) (ws + 0);           // 25,600,000
    float*  t_msg  = (float*) (ws + 25600000);    // 12,800,000
    double* es_d   = (double*)(ws + 38400000);    //    800,000
    double* et_d   = (double*)(ws + 39200000);    //    400,000
    int*    cnt_r  = (int*)   (ws + 39600000);    //    200,000
    int*    cnt_c  = (int*)   (ws + 39800000);    //    400,000
    int*    ptr_r  = (int*)   (ws + 40200000);    //    200,004
    int*    ptr_c  = (int*)   (ws + 40400004);    //    400,004 (+8 pad)
    int*    rank_r = (int*)   (ws + 40800016);    //  4,000,000
    int*    rank_c = (int*)   (ws + 44800016);    //  4,000,000
    unsigned long long* srtT = (unsigned long long*)(ws + 48800016); // 8,000,000
    unsigned long long* srtS = (unsigned long long*)(ws + 56800016); // 8,000,000

    hipMemsetAsync(ws + 39600000, 0, 600000, stream);  // cnt_r + cnt_c

    fused_gemm_hist<<<NHIST + GBLK, 256, 0, stream>>>(
        x_source, x_target, w_s, w_t, att,
        s_msg, t_msg, es_d, et_d,
        rows, cols, cnt_r, cnt_c, rank_r, rank_c);

    scan_two<<<2, 1024, 0, stream>>>(cnt_r, cnt_c, ptr_r, ptr_c);
    scatter_part<<<2048, 256, 0, stream>>>(
        rows, cols, nbhd, ptr_r, ptr_c, rank_r, rank_c, srtT, srtS);

    gather_both<<<(N_TGT + N_SRC + 3) / 4, 256, 0, stream>>>(
        (const int2*)srtT, ptr_r, s_msg, msg_tgt,
        (const int2*)srtS, ptr_c, t_msg, msg_src, es_d, et_d);
}

// Round 16
// 296.374 us; speedup vs baseline: 1.1941x; 1.0038x over previous
//
#include <hip/hip_runtime.h>

#define N_SRC   100000
#define N_TGT   50000
#define N_EDGES 1000000
#define NEG     0.2
#define NXCD    8
#define TPART   (N_TGT / NXCD)   // 6250
#define SPART   (N_SRC / NXCD)   // 12500

#define GBLK_S  1563             // ceil(N_SRC/64)
#define GBLK_T  782              // ceil(N_TGT/64)
#define GBLK    (GBLK_S + GBLK_T)          // 2345 gemm blocks
#define NHIST   640              // hist blocks, grid-stride, dispatched FIRST

// ===========================================================================
// R16: hist loop 4x-unrolled (4 atomic pairs in flight per thread), NHIST
// 1280->640; gemm half1 async-staged (loads issued before half0 compute);
// gather payload via nontemporal loads. Everything else = R15 (297 us).
// ===========================================================================

// ---------------------------------------------------------------------------
#define XS2 65
__global__ __launch_bounds__(256) void fused_gemm_hist(
    const float* __restrict__ x_source, const float* __restrict__ x_target,
    const float* __restrict__ w_s, const float* __restrict__ w_t,
    const float* __restrict__ att,
    float* __restrict__ s_msg, float* __restrict__ t_msg,
    double* __restrict__ es_d, double* __restrict__ et_d,
    const int* __restrict__ rows, const int* __restrict__ cols,
    int* __restrict__ cnt_r, int* __restrict__ cnt_c,
    int* __restrict__ rank_r, int* __restrict__ rank_c)
{
    __shared__ float xs[64 * XS2];         // 16.6 KB
    __shared__ double eds[4][64];          //  2.0 KB
    const int tid = threadIdx.x;

    if (blockIdx.x < NHIST) {
        // ------- hist branch: dispatched first, grid-stride, 4x unrolled ------
        const int S = NHIST * 256;
        int i = blockIdx.x * 256 + tid;
        for (; i + 3 * S < N_EDGES; i += 4 * S) {
            const int r0 = rows[i],         c0_ = cols[i];
            const int r1 = rows[i + S],     c1_ = cols[i + S];
            const int r2 = rows[i + 2 * S], c2_ = cols[i + 2 * S];
            const int r3 = rows[i + 3 * S], c3_ = cols[i + 3 * S];
            const int kr0 = atomicAdd(&cnt_r[r0], 1);
            const int kc0 = atomicAdd(&cnt_c[c0_], 1);
            const int kr1 = atomicAdd(&cnt_r[r1], 1);
            const int kc1 = atomicAdd(&cnt_c[c1_], 1);
            const int kr2 = atomicAdd(&cnt_r[r2], 1);
            const int kc2 = atomicAdd(&cnt_c[c2_], 1);
            const int kr3 = atomicAdd(&cnt_r[r3], 1);
            const int kc3 = atomicAdd(&cnt_c[c3_], 1);
            rank_r[i]         = kr0; rank_c[i]         = kc0;
            rank_r[i + S]     = kr1; rank_c[i + S]     = kc1;
            rank_r[i + 2 * S] = kr2; rank_c[i + 2 * S] = kc2;
            rank_r[i + 3 * S] = kr3; rank_c[i + 3 * S] = kc3;
        }
        for (; i < N_EDGES; i += S) {
            rank_r[i] = atomicAdd(&cnt_r[rows[i]], 1);
            rank_c[i] = atomicAdd(&cnt_c[cols[i]], 1);
        }
        return;
    }

    // ---------------- gemm branch ----------------
    const int gi = blockIdx.x - NHIST;

    const float* x; const float* w; int att_off, nrows, bblk;
    float* msg; double* evec;
    if (gi < GBLK_S) { x = x_source; w = w_s; att_off = 0;  nrows = N_SRC;
                       msg = s_msg;  evec = es_d; bblk = gi; }
    else             { x = x_target; w = w_t; att_off = 64; nrows = N_TGT;
                       msg = t_msg;  evec = et_d; bblk = gi - GBLK_S; }

    const int lane = tid & 63;
    const int part = tid >> 6;
    const int c0   = __builtin_amdgcn_readfirstlane(part << 4);
    const int row0 = bblk * 64;
    const int row  = row0 + lane;
    const bool act = row < nrows;

    float acc[16];
    #pragma unroll
    for (int c = 0; c < 16; ++c) acc[c] = 0.f;

    const int xbase = lane * XS2;

    // ---- stage half0 ----
    #pragma unroll
    for (int it = 0; it < 4; ++it) {
        const int fid = tid + it * 256;
        const int r = fid >> 4, q = fid & 15;
        if (row0 + r < nrows) {
            const float4 v = *(const float4*)(x + (size_t)(row0 + r) * 128 + 4 * q);
            float* d = &xs[r * XS2 + 4 * q];
            d[0] = v.x; d[1] = v.y; d[2] = v.z; d[3] = v.w;
        }
    }
    __syncthreads();

    // ---- issue half1 loads (in flight during half0 compute) ----
    float4 pre[4];
    #pragma unroll
    for (int it = 0; it < 4; ++it) {
        const int fid = tid + it * 256;
        const int r = fid >> 4, q = fid & 15;
        pre[it] = (row0 + r < nrows)
            ? *(const float4*)(x + (size_t)(row0 + r) * 128 + 64 + 4 * q)
            : make_float4(0.f, 0.f, 0.f, 0.f);
    }

    // ---- compute half0 ----
    for (int kc = 0; kc < 64; kc += 16) {
        #pragma unroll
        for (int kk = 0; kk < 16; ++kk) {
            const float xk = xs[xbase + kc + kk];
            const float* wr = w + (size_t)(kc + kk) * 64 + c0;   // scalar addr
            #pragma unroll
            for (int c = 0; c < 16; ++c)
                acc[c] = fmaf(xk, wr[c], acc[c]);
        }
    }
    __syncthreads();

    // ---- write half1 to LDS ----
    #pragma unroll
    for (int it = 0; it < 4; ++it) {
        const int fid = tid + it * 256;
        const int r = fid >> 4, q = fid & 15;
        float* d = &xs[r * XS2 + 4 * q];
        d[0] = pre[it].x; d[1] = pre[it].y; d[2] = pre[it].z; d[3] = pre[it].w;
    }
    __syncthreads();

    // ---- compute half1 ----
    for (int kc = 0; kc < 64; kc += 16) {
        #pragma unroll
        for (int kk = 0; kk < 16; ++kk) {
            const float xk = xs[xbase + kc + kk];
            const float* wr = w + (size_t)(64 + kc + kk) * 64 + c0;
            #pragma unroll
            for (int c = 0; c < 16; ++c)
                acc[c] = fmaf(xk, wr[c], acc[c]);
        }
    }

    double e = 0.0;
    #pragma unroll
    for (int c = 0; c < 16; ++c)
        e += (double)acc[c] * (double)att[att_off + c0 + c];
    eds[part][lane] = e;
    __syncthreads();
    if (part == 0 && act)
        evec[row] = eds[0][lane] + eds[1][lane] + eds[2][lane] + eds[3][lane];

    if (act) {
        float* mo = msg + (size_t)row * 64 + c0;
        #pragma unroll
        for (int q = 0; q < 4; ++q)
            *(float4*)(mo + 4 * q) = *(float4*)(acc + 4 * q);
    }
}

// ---------------------------------------------------------------------------
// Exclusive scan, tiled + coalesced. block 0 -> rows (N_TGT), 1 -> cols (N_SRC).
// ---------------------------------------------------------------------------
__global__ __launch_bounds__(1024) void scan_two(
    const int* __restrict__ cnt_r, const int* __restrict__ cnt_c,
    int* __restrict__ ptr_r, int* __restrict__ ptr_c)
{
    const int n    = blockIdx.x ? N_SRC : N_TGT;
    const int* cnt = blockIdx.x ? cnt_c : cnt_r;
    int* ptr       = blockIdx.x ? ptr_c : ptr_r;
    const int tid  = threadIdx.x;
    const int lane = tid & 63, wid = tid >> 6;

    __shared__ int wsum[16];
    __shared__ int s_carry;
    if (tid == 0) s_carry = 0;
    __syncthreads();

    for (int base = 0; base < n; base += 4096) {
        const int idx = base + tid * 4;
        int4 v = make_int4(0, 0, 0, 0);
        if (idx + 3 < n) {
            v = *(const int4*)(cnt + idx);
        } else if (idx < n) {
            v.x = cnt[idx];
            if (idx + 1 < n) v.y = cnt[idx + 1];
            if (idx + 2 < n) v.z = cnt[idx + 2];
        }
        const int s = v.x + v.y + v.z + v.w;

        int p = s;
        #pragma unroll
        for (int d = 1; d < 64; d <<= 1) {
            int t = __shfl_up(p, d);
            if (lane >= d) p += t;
        }
        if (lane == 63) wsum[wid] = p;
        __syncthreads();
        if (tid == 0) {
            int a = 0;
            #pragma unroll
            for (int i = 0; i < 16; ++i) { int t = wsum[i]; wsum[i] = a; a += t; }
        }
        __syncthreads();

        int run = s_carry + wsum[wid] + (p - s);
        if (idx     < n) ptr[idx]     = run; run += v.x;
        if (idx + 1 < n) ptr[idx + 1] = run; run += v.y;
        if (idx + 2 < n) ptr[idx + 2] = run; run += v.z;
        if (idx + 3 < n) ptr[idx + 3] = run; run += v.w;

        __syncthreads();
        if (tid == 1023) s_carry = run;
        __syncthreads();
    }
    if (tid == 0) ptr[n] = s_carry;
}

// ---------------------------------------------------------------------------
// Scatter, XCD-partitioned (R8) + atomic-free (R12): slot = ptr[node]+rank[i].
// ---------------------------------------------------------------------------
__global__ __launch_bounds__(256) void scatter_part(
    const int* __restrict__ rows, const int* __restrict__ cols,
    const float* __restrict__ nbhd,
    const int* __restrict__ ptr_r, const int* __restrict__ ptr_c,
    const int* __restrict__ rank_r, const int* __restrict__ rank_c,
    unsigned long long* __restrict__ srtT, unsigned long long* __restrict__ srtS)
{
    const int xcd  = blockIdx.x & (NXCD - 1);
    const int ibx  = blockIdx.x >> 3;
    const int step = (gridDim.x >> 3) * blockDim.x;
    const int lo_r = xcd * TPART, lo_c = xcd * SPART;

    for (int i = ibx * blockDim.x + threadIdx.x; i < N_EDGES; i += step) {
        const int r = rows[i], c = cols[i];
        const bool mr = (unsigned)(r - lo_r) < TPART;
        const bool mc = (unsigned)(c - lo_c) < SPART;
        if (!(mr | mc)) continue;
        const unsigned long long nb =
            (unsigned long long)(unsigned)__float_as_int(nbhd[i]) << 32;
        if (mr) srtT[ptr_r[r] + rank_r[i]] = nb | (unsigned)c;
        if (mc) srtS[ptr_c[c] + rank_c[i]] = nb | (unsigned)r;
    }
}

// ---------------------------------------------------------------------------
// Gather: one wave per output row, lane = feature. den f64 (cancelling sum);
// numerator f32 x4 (R15-proven). Payload via nontemporal loads (stream-once).
// ---------------------------------------------------------------------------
__global__ __launch_bounds__(256) void gather_both(
    const unsigned long long* __restrict__ srtT, const int* __restrict__ ptr_r,
    const float* __restrict__ s_msg, float* __restrict__ msg_tgt,
    const unsigned long long* __restrict__ srtS, const int* __restrict__ ptr_c,
    const float* __restrict__ t_msg, float* __restrict__ msg_src,
    const double* __restrict__ es_d, const double* __restrict__ et_d)
{
    const int gw   = (blockIdx.x * blockDim.x + threadIdx.x) >> 6;
    const int lane = threadIdx.x & 63;

    const unsigned long long* srt; const int* ptr; const float* min_; float* out;
    const double* other_d; double base; int row;
    if (gw < N_TGT) {
        srt = srtT; ptr = ptr_r; min_ = s_msg; out = msg_tgt;
        other_d = es_d; row = gw; base = et_d[row];
    } else {
        row = gw - N_TGT;
        if (row >= N_SRC) return;
        srt = srtS; ptr = ptr_c; min_ = t_msg; out = msg_src;
        other_d = et_d; base = es_d[row];
    }

    const int b = ptr[row], e = ptr[row + 1];
    double den = 0.0;
    float a0 = 0.f, a1 = 0.f, a2 = 0.f, a3 = 0.f;

    for (int j0 = b; j0 < e; j0 += 64) {
        const int m = e - j0;
        int oidx = 0; double v = 0.0; float wf = 0.f;
        if (lane < m) {
            const unsigned long long pv = __builtin_nontemporal_load(&srt[j0 + lane]);
            oidx = (int)(unsigned)(pv & 0xFFFFFFFFull);
            const float nb = __int_as_float((int)(unsigned)(pv >> 32));
            const double sv = base + other_d[oidx];
            v = (sv >= 0.0) ? sv : NEG * sv;
            wf = (float)(v * (double)nb);
        }
        den += v;

        const int cnt = m < 64 ? m : 64;
        int j = 0;
        for (; j + 3 < cnt; j += 4) {
            const int   c0_ = __shfl(oidx, j);     const float w0 = __shfl(wf, j);
            const int   c1_ = __shfl(oidx, j + 1); const float w1 = __shfl(wf, j + 1);
            const int   c2_ = __shfl(oidx, j + 2); const float w2 = __shfl(wf, j + 2);
            const int   c3_ = __shfl(oidx, j + 3); const float w3 = __shfl(wf, j + 3);
            a0 = fmaf(w0, min_[(size_t)c0_ * 64 + lane], a0);
            a1 = fmaf(w1, min_[(size_t)c1_ * 64 + lane], a1);
            a2 = fmaf(w2, min_[(size_t)c2_ * 64 + lane], a2);
            a3 = fmaf(w3, min_[(size_t)c3_ * 64 + lane], a3);
        }
        for (; j < cnt; ++j) {
            const int   c = __shfl(oidx, j);
            const float w = __shfl(wf, j);
            a0 = fmaf(w, min_[(size_t)c * 64 + lane], a0);
        }
    }
    #pragma unroll
    for (int s = 32; s; s >>= 1) den += __shfl_xor(den, s);
    const double inv = (den != 0.0) ? 1.0 / den : 0.0;
    const double acc = (double)((a0 + a1) + (a2 + a3));
    out[(size_t)row * 64 + lane] = (float)(acc * inv);
}

// ===========================================================================
extern "C" void kernel_launch(void* const* d_in, const int* in_sizes, int n_in,
                              void* d_out, int out_size, void* d_ws, size_t ws_size,
                              hipStream_t stream)
{
    const float* x_source = (const float*)d_in[0];
    const float* x_target = (const float*)d_in[1];
    const float* w_s      = (const float*)d_in[2];
    const float* w_t      = (const float*)d_in[3];
    const float* att      = (const float*)d_in[4];
    const float* nbhd     = (const float*)d_in[5];
    const int*   rows     = (const int*)d_in[6];
    const int*   cols     = (const int*)d_in[7];

    float* out     = (float*)d_out;
    float* msg_src = out;                       // (N_SRC, 64)
    float* msg_tgt = out + (size_t)N_SRC * 64;  // (N_TGT, 64)

    char* ws = (char*)d_ws;
    // byte layout: total 65,400,016 B
    float*  s_msg  = (float*) (ws + 0);           // 25,600,000
    float*  t_msg  = (float*) (ws + 25600000);    // 12,800,000
    double* es_d   = (double*)(ws + 38400000);    //    800,000
    double* et_d   = (double*)(ws + 39200000);    //    400,000
    int*    cnt_r  = (int*)   (ws + 39600000);    //    200,000
    int*    cnt_c  = (int*)   (ws + 39800000);    //    400,000
    int*    ptr_r  = (int*)   (ws + 40200000);    //    200,004
    int*    ptr_c  = (int*)   (ws + 40400004);    //    400,004 (+8 pad)
    int*    rank_r = (int*)   (ws + 40800016);    //  4,000,000
    int*    rank_c = (int*)   (ws + 44800016);    //  4,000,000
    unsigned long long* srtT = (unsigned long long*)(ws + 48800016); // 8,000,000
    unsigned long long* srtS = (unsigned long long*)(ws + 56800016); // 8,000,000

    hipMemsetAsync(ws + 39600000, 0, 600000, stream);  // cnt_r + cnt_c

    fused_gemm_hist<<<NHIST + GBLK, 256, 0, stream>>>(
        x_source, x_target, w_s, w_t, att,
        s_msg, t_msg, es_d, et_d,
        rows, cols, cnt_r, cnt_c, rank_r, rank_c);

    scan_two<<<2, 1024, 0, stream>>>(cnt_r, cnt_c, ptr_r, ptr_c);
    scatter_part<<<2048, 256, 0, stream>>>(
        rows, cols, nbhd, ptr_r, ptr_c, rank_r, rank_c, srtT, srtS);

    gather_both<<<(N_TGT + N_SRC + 3) / 4, 256, 0, stream>>>(
        srtT, ptr_r, s_msg, msg_tgt,
        srtS, ptr_c, t_msg, msg_src, es_d, et_d);
}

// Round 17
// 282.601 us; speedup vs baseline: 1.2523x; 1.0487x over previous
//
#include <hip/hip_runtime.h>

#define N_SRC   100000
#define N_TGT   50000
#define N_EDGES 1000000
#define NEG     0.2
#define NXCD    8
#define TPART   (N_TGT / NXCD)   // 6250
#define SPART   (N_SRC / NXCD)   // 12500

#define GBLK_S  1563             // ceil(N_SRC/64)
#define GBLK_T  782              // ceil(N_TGT/64)
#define GBLK    (GBLK_S + GBLK_T)          // 2345 gemm blocks
#define NHIST   640              // hist blocks, grid-stride, dispatched FIRST

// ===========================================================================
// R17: (1) gather NT payload load reverted (R16: −13 us regression — payload
// is L2-hot from scatter); (2) hist packs (node|rank) into one int per side
// (rows<2^16, rank<<16; cols<2^17, rank<<17 — Poisson max-degree ~41/27,
// huge margin) so scatter reads 3 arrays instead of 5: 160->96 MB.
// ===========================================================================

// ---------------------------------------------------------------------------
#define XS2 65
__global__ __launch_bounds__(256) void fused_gemm_hist(
    const float* __restrict__ x_source, const float* __restrict__ x_target,
    const float* __restrict__ w_s, const float* __restrict__ w_t,
    const float* __restrict__ att,
    float* __restrict__ s_msg, float* __restrict__ t_msg,
    double* __restrict__ es_d, double* __restrict__ et_d,
    const int* __restrict__ rows, const int* __restrict__ cols,
    int* __restrict__ cnt_r, int* __restrict__ cnt_c,
    unsigned* __restrict__ packT, unsigned* __restrict__ packC)
{
    __shared__ float xs[64 * XS2];         // 16.6 KB
    __shared__ double eds[4][64];          //  2.0 KB
    const int tid = threadIdx.x;

    if (blockIdx.x < NHIST) {
        // ------- hist branch: dispatched first, grid-stride, 4x unrolled ------
        const int S = NHIST * 256;
        int i = blockIdx.x * 256 + tid;
        for (; i + 3 * S < N_EDGES; i += 4 * S) {
            const unsigned r0 = rows[i],         c0_ = cols[i];
            const unsigned r1 = rows[i + S],     c1_ = cols[i + S];
            const unsigned r2 = rows[i + 2 * S], c2_ = cols[i + 2 * S];
            const unsigned r3 = rows[i + 3 * S], c3_ = cols[i + 3 * S];
            const unsigned kr0 = atomicAdd(&cnt_r[r0], 1);
            const unsigned kc0 = atomicAdd(&cnt_c[c0_], 1);
            const unsigned kr1 = atomicAdd(&cnt_r[r1], 1);
            const unsigned kc1 = atomicAdd(&cnt_c[c1_], 1);
            const unsigned kr2 = atomicAdd(&cnt_r[r2], 1);
            const unsigned kc2 = atomicAdd(&cnt_c[c2_], 1);
            const unsigned kr3 = atomicAdd(&cnt_r[r3], 1);
            const unsigned kc3 = atomicAdd(&cnt_c[c3_], 1);
            packT[i]         = r0 | (kr0 << 16); packC[i]         = c0_ | (kc0 << 17);
            packT[i + S]     = r1 | (kr1 << 16); packC[i + S]     = c1_ | (kc1 << 17);
            packT[i + 2 * S] = r2 | (kr2 << 16); packC[i + 2 * S] = c2_ | (kc2 << 17);
            packT[i + 3 * S] = r3 | (kr3 << 16); packC[i + 3 * S] = c3_ | (kc3 << 17);
        }
        for (; i < N_EDGES; i += S) {
            const unsigned r = rows[i], c = cols[i];
            packT[i] = r | ((unsigned)atomicAdd(&cnt_r[r], 1) << 16);
            packC[i] = c | ((unsigned)atomicAdd(&cnt_c[c], 1) << 17);
        }
        return;
    }

    // ---------------- gemm branch ----------------
    const int gi = blockIdx.x - NHIST;

    const float* x; const float* w; int att_off, nrows, bblk;
    float* msg; double* evec;
    if (gi < GBLK_S) { x = x_source; w = w_s; att_off = 0;  nrows = N_SRC;
                       msg = s_msg;  evec = es_d; bblk = gi; }
    else             { x = x_target; w = w_t; att_off = 64; nrows = N_TGT;
                       msg = t_msg;  evec = et_d; bblk = gi - GBLK_S; }

    const int lane = tid & 63;
    const int part = tid >> 6;
    const int c0   = __builtin_amdgcn_readfirstlane(part << 4);
    const int row0 = bblk * 64;
    const int row  = row0 + lane;
    const bool act = row < nrows;

    float acc[16];
    #pragma unroll
    for (int c = 0; c < 16; ++c) acc[c] = 0.f;

    const int xbase = lane * XS2;

    // ---- stage half0 ----
    #pragma unroll
    for (int it = 0; it < 4; ++it) {
        const int fid = tid + it * 256;
        const int r = fid >> 4, q = fid & 15;
        if (row0 + r < nrows) {
            const float4 v = *(const float4*)(x + (size_t)(row0 + r) * 128 + 4 * q);
            float* d = &xs[r * XS2 + 4 * q];
            d[0] = v.x; d[1] = v.y; d[2] = v.z; d[3] = v.w;
        }
    }
    __syncthreads();

    // ---- issue half1 loads (in flight during half0 compute) ----
    float4 pre[4];
    #pragma unroll
    for (int it = 0; it < 4; ++it) {
        const int fid = tid + it * 256;
        const int r = fid >> 4, q = fid & 15;
        pre[it] = (row0 + r < nrows)
            ? *(const float4*)(x + (size_t)(row0 + r) * 128 + 64 + 4 * q)
            : make_float4(0.f, 0.f, 0.f, 0.f);
    }

    // ---- compute half0 ----
    for (int kc = 0; kc < 64; kc += 16) {
        #pragma unroll
        for (int kk = 0; kk < 16; ++kk) {
            const float xk = xs[xbase + kc + kk];
            const float* wr = w + (size_t)(kc + kk) * 64 + c0;   // scalar addr
            #pragma unroll
            for (int c = 0; c < 16; ++c)
                acc[c] = fmaf(xk, wr[c], acc[c]);
        }
    }
    __syncthreads();

    // ---- write half1 to LDS ----
    #pragma unroll
    for (int it = 0; it < 4; ++it) {
        const int fid = tid + it * 256;
        const int r = fid >> 4, q = fid & 15;
        float* d = &xs[r * XS2 + 4 * q];
        d[0] = pre[it].x; d[1] = pre[it].y; d[2] = pre[it].z; d[3] = pre[it].w;
    }
    __syncthreads();

    // ---- compute half1 ----
    for (int kc = 0; kc < 64; kc += 16) {
        #pragma unroll
        for (int kk = 0; kk < 16; ++kk) {
            const float xk = xs[xbase + kc + kk];
            const float* wr = w + (size_t)(64 + kc + kk) * 64 + c0;
            #pragma unroll
            for (int c = 0; c < 16; ++c)
                acc[c] = fmaf(xk, wr[c], acc[c]);
        }
    }

    double e = 0.0;
    #pragma unroll
    for (int c = 0; c < 16; ++c)
        e += (double)acc[c] * (double)att[att_off + c0 + c];
    eds[part][lane] = e;
    __syncthreads();
    if (part == 0 && act)
        evec[row] = eds[0][lane] + eds[1][lane] + eds[2][lane] + eds[3][lane];

    if (act) {
        float* mo = msg + (size_t)row * 64 + c0;
        #pragma unroll
        for (int q = 0; q < 4; ++q)
            *(float4*)(mo + 4 * q) = *(float4*)(acc + 4 * q);
    }
}

// ---------------------------------------------------------------------------
// Exclusive scan, tiled + coalesced. block 0 -> rows (N_TGT), 1 -> cols (N_SRC).
// ---------------------------------------------------------------------------
__global__ __launch_bounds__(1024) void scan_two(
    const int* __restrict__ cnt_r, const int* __restrict__ cnt_c,
    int* __restrict__ ptr_r, int* __restrict__ ptr_c)
{
    const int n    = blockIdx.x ? N_SRC : N_TGT;
    const int* cnt = blockIdx.x ? cnt_c : cnt_r;
    int* ptr       = blockIdx.x ? ptr_c : ptr_r;
    const int tid  = threadIdx.x;
    const int lane = tid & 63, wid = tid >> 6;

    __shared__ int wsum[16];
    __shared__ int s_carry;
    if (tid == 0) s_carry = 0;
    __syncthreads();

    for (int base = 0; base < n; base += 4096) {
        const int idx = base + tid * 4;
        int4 v = make_int4(0, 0, 0, 0);
        if (idx + 3 < n) {
            v = *(const int4*)(cnt + idx);
        } else if (idx < n) {
            v.x = cnt[idx];
            if (idx + 1 < n) v.y = cnt[idx + 1];
            if (idx + 2 < n) v.z = cnt[idx + 2];
        }
        const int s = v.x + v.y + v.z + v.w;

        int p = s;
        #pragma unroll
        for (int d = 1; d < 64; d <<= 1) {
            int t = __shfl_up(p, d);
            if (lane >= d) p += t;
        }
        if (lane == 63) wsum[wid] = p;
        __syncthreads();
        if (tid == 0) {
            int a = 0;
            #pragma unroll
            for (int i = 0; i < 16; ++i) { int t = wsum[i]; wsum[i] = a; a += t; }
        }
        __syncthreads();

        int run = s_carry + wsum[wid] + (p - s);
        if (idx     < n) ptr[idx]     = run; run += v.x;
        if (idx + 1 < n) ptr[idx + 1] = run; run += v.y;
        if (idx + 2 < n) ptr[idx + 2] = run; run += v.z;
        if (idx + 3 < n) ptr[idx + 3] = run; run += v.w;

        __syncthreads();
        if (tid == 1023) s_carry = run;
        __syncthreads();
    }
    if (tid == 0) ptr[n] = s_carry;
}

// ---------------------------------------------------------------------------
// Scatter, XCD-partitioned (R8) + atomic-free (R12), packed inputs (R17):
// reads packT/packC/nbhd only. slot = ptr[node] + rank.
// ---------------------------------------------------------------------------
__global__ __launch_bounds__(256) void scatter_part(
    const unsigned* __restrict__ packT, const unsigned* __restrict__ packC,
    const float* __restrict__ nbhd,
    const int* __restrict__ ptr_r, const int* __restrict__ ptr_c,
    unsigned long long* __restrict__ srtT, unsigned long long* __restrict__ srtS)
{
    const int xcd  = blockIdx.x & (NXCD - 1);
    const int ibx  = blockIdx.x >> 3;
    const int step = (gridDim.x >> 3) * blockDim.x;
    const unsigned lo_r = xcd * TPART, lo_c = xcd * SPART;

    for (int i = ibx * blockDim.x + threadIdx.x; i < N_EDGES; i += step) {
        const unsigned pT = packT[i], pC = packC[i];
        const unsigned r = pT & 0xFFFFu,  kr = pT >> 16;
        const unsigned c = pC & 0x1FFFFu, kc = pC >> 17;
        const bool mr = (r - lo_r) < TPART;
        const bool mc = (c - lo_c) < SPART;
        if (!(mr | mc)) continue;
        const unsigned long long nb =
            (unsigned long long)(unsigned)__float_as_int(nbhd[i]) << 32;
        if (mr) srtT[ptr_r[r] + kr] = nb | c;
        if (mc) srtS[ptr_c[c] + kc] = nb | r;
    }
}

// ---------------------------------------------------------------------------
// Gather (R15 version — plain payload loads): one wave per output row,
// lane = feature. den f64 (cancelling sum); numerator f32 x4.
// ---------------------------------------------------------------------------
__global__ __launch_bounds__(256) void gather_both(
    const int2* __restrict__ srtT, const int* __restrict__ ptr_r,
    const float* __restrict__ s_msg, float* __restrict__ msg_tgt,
    const int2* __restrict__ srtS, const int* __restrict__ ptr_c,
    const float* __restrict__ t_msg, float* __restrict__ msg_src,
    const double* __restrict__ es_d, const double* __restrict__ et_d)
{
    const int gw   = (blockIdx.x * blockDim.x + threadIdx.x) >> 6;
    const int lane = threadIdx.x & 63;

    const int2* srt; const int* ptr; const float* min_; float* out;
    const double* other_d; double base; int row;
    if (gw < N_TGT) {
        srt = srtT; ptr = ptr_r; min_ = s_msg; out = msg_tgt;
        other_d = es_d; row = gw; base = et_d[row];
    } else {
        row = gw - N_TGT;
        if (row >= N_SRC) return;
        srt = srtS; ptr = ptr_c; min_ = t_msg; out = msg_src;
        other_d = et_d; base = es_d[row];
    }

    const int b = ptr[row], e = ptr[row + 1];
    double den = 0.0;
    float a0 = 0.f, a1 = 0.f, a2 = 0.f, a3 = 0.f;

    for (int j0 = b; j0 < e; j0 += 64) {
        const int m = e - j0;
        int oidx = 0; double v = 0.0; float wf = 0.f;
        if (lane < m) {
            const int2 pay = srt[j0 + lane];
            oidx = pay.x;
            const float nb = __int_as_float(pay.y);
            const double sv = base + other_d[oidx];
            v = (sv >= 0.0) ? sv : NEG * sv;
            wf = (float)(v * (double)nb);
        }
        den += v;

        const int cnt = m < 64 ? m : 64;
        int j = 0;
        for (; j + 3 < cnt; j += 4) {
            const int   c0_ = __shfl(oidx, j);     const float w0 = __shfl(wf, j);
            const int   c1_ = __shfl(oidx, j + 1); const float w1 = __shfl(wf, j + 1);
            const int   c2_ = __shfl(oidx, j + 2); const float w2 = __shfl(wf, j + 2);
            const int   c3_ = __shfl(oidx, j + 3); const float w3 = __shfl(wf, j + 3);
            a0 = fmaf(w0, min_[(size_t)c0_ * 64 + lane], a0);
            a1 = fmaf(w1, min_[(size_t)c1_ * 64 + lane], a1);
            a2 = fmaf(w2, min_[(size_t)c2_ * 64 + lane], a2);
            a3 = fmaf(w3, min_[(size_t)c3_ * 64 + lane], a3);
        }
        for (; j < cnt; ++j) {
            const int   c = __shfl(oidx, j);
            const float w = __shfl(wf, j);
            a0 = fmaf(w, min_[(size_t)c * 64 + lane], a0);
        }
    }
    #pragma unroll
    for (int s = 32; s; s >>= 1) den += __shfl_xor(den, s);
    const double inv = (den != 0.0) ? 1.0 / den : 0.0;
    const double acc = (double)((a0 + a1) + (a2 + a3));
    out[(size_t)row * 64 + lane] = (float)(acc * inv);
}

// ===========================================================================
extern "C" void kernel_launch(void* const* d_in, const int* in_sizes, int n_in,
                              void* d_out, int out_size, void* d_ws, size_t ws_size,
                              hipStream_t stream)
{
    const float* x_source = (const float*)d_in[0];
    const float* x_target = (const float*)d_in[1];
    const float* w_s      = (const float*)d_in[2];
    const float* w_t      = (const float*)d_in[3];
    const float* att      = (const float*)d_in[4];
    const float* nbhd     = (const float*)d_in[5];
    const int*   rows     = (const int*)d_in[6];
    const int*   cols     = (const int*)d_in[7];

    float* out     = (float*)d_out;
    float* msg_src = out;                       // (N_SRC, 64)
    float* msg_tgt = out + (size_t)N_SRC * 64;  // (N_TGT, 64)

    char* ws = (char*)d_ws;
    // byte layout: total 65,400,016 B
    float*    s_msg  = (float*)   (ws + 0);           // 25,600,000
    float*    t_msg  = (float*)   (ws + 25600000);    // 12,800,000
    double*   es_d   = (double*)  (ws + 38400000);    //    800,000
    double*   et_d   = (double*)  (ws + 39200000);    //    400,000
    int*      cnt_r  = (int*)     (ws + 39600000);    //    200,000
    int*      cnt_c  = (int*)     (ws + 39800000);    //    400,000
    int*      ptr_r  = (int*)     (ws + 40200000);    //    200,004
    int*      ptr_c  = (int*)     (ws + 40400004);    //    400,004 (+8 pad)
    unsigned* packT  = (unsigned*)(ws + 40800016);    //  4,000,000
    unsigned* packC  = (unsigned*)(ws + 44800016);    //  4,000,000
    unsigned long long* srtT = (unsigned long long*)(ws + 48800016); // 8,000,000
    unsigned long long* srtS = (unsigned long long*)(ws + 56800016); // 8,000,000

    hipMemsetAsync(ws + 39600000, 0, 600000, stream);  // cnt_r + cnt_c

    fused_gemm_hist<<<NHIST + GBLK, 256, 0, stream>>>(
        x_source, x_target, w_s, w_t, att,
        s_msg, t_msg, es_d, et_d,
        rows, cols, cnt_r, cnt_c, packT, packC);

    scan_two<<<2, 1024, 0, stream>>>(cnt_r, cnt_c, ptr_r, ptr_c);
    scatter_part<<<2048, 256, 0, stream>>>(
        packT, packC, nbhd, ptr_r, ptr_c, srtT, srtS);

    gather_both<<<(N_TGT + N_SRC + 3) / 4, 256, 0, stream>>>(
        (const int2*)srtT, ptr_r, s_msg, msg_tgt,
        (const int2*)srtS, ptr_c, t_msg, msg_src, es_d, et_d);
}